// Round 3
// baseline (79978.082 us; speedup 1.0000x reference)
//
#include <hip/hip_runtime.h>
#include <math.h>

#define BB 64
#define TT 512
#define HH 512
#define KK 512
#define G3 1536
#define PEN 0.7f
#define NBLK 256
#define NTHR 512
#define WSTRIDE ((size_t)(G3 * KK))

// ---------------------------------------------------------------------------
// flat grid barrier: release-RMW arrival, relaxed spin, one acquire at exit.
__device__ __forceinline__ void gbar(unsigned* cnt, unsigned target) {
  __syncthreads();
  if (threadIdx.x == 0) {
    __hip_atomic_fetch_add(cnt, 1u, __ATOMIC_RELEASE, __HIP_MEMORY_SCOPE_AGENT);
    while (__hip_atomic_load(cnt, __ATOMIC_RELAXED, __HIP_MEMORY_SCOPE_AGENT) < target)
      __builtin_amdgcn_s_sleep(2);
    (void)__hip_atomic_load(cnt, __ATOMIC_ACQUIRE, __HIP_MEMORY_SCOPE_AGENT);
  }
  __syncthreads();
}

// ---------------------------------------------------------------------------
// pre 1: xc[t][s] = sum_b x[b,t,:] . Wsel[s,512:] + B*bsel[s]
__global__ void k_pre_xc(const float* __restrict__ x, const float* __restrict__ Wsel,
                         const float* __restrict__ bsel, float* __restrict__ xc) {
  int t = blockIdx.x, tid = threadIdx.x;
  __shared__ float xs[512];
  __shared__ float a0[256], a1[256], a2[256];
  for (int i = tid; i < 512; i += 256) {
    float s = 0.f;
    const float* px = x + (size_t)t * KK + i;
    for (int b = 0; b < BB; ++b) s += px[(size_t)b * TT * KK];
    xs[i] = s;
  }
  __syncthreads();
  float c0 = 0.f, c1 = 0.f, c2 = 0.f;
  for (int i = tid; i < 512; i += 256) {
    float v = xs[i];
    c0 += v * Wsel[512 + i];
    c1 += v * Wsel[1024 + 512 + i];
    c2 += v * Wsel[2048 + 512 + i];
  }
  a0[tid] = c0; a1[tid] = c1; a2[tid] = c2;
  __syncthreads();
  for (int off = 128; off; off >>= 1) {
    if (tid < off) { a0[tid] += a0[tid + off]; a1[tid] += a1[tid + off]; a2[tid] += a2[tid + off]; }
    __syncthreads();
  }
  if (tid == 0) {
    xc[t * 4 + 0] = a0[0] + 64.f * bsel[0];
    xc[t * 4 + 1] = a1[0] + 64.f * bsel[1];
    xc[t * 4 + 2] = a2[0] + 64.f * bsel[2];
  }
}

// pre 2: wsum (col-sums of Wlw), bsum, counter = 0
__global__ void k_pre_misc(const float* __restrict__ Wlw, const float* __restrict__ blw,
                           float* __restrict__ wsum, float* __restrict__ bsumb,
                           unsigned* __restrict__ cnt) {
  int tid = threadIdx.x;
  for (int h = tid; h < 512; h += 256) {
    float s = 0.f;
    for (int g = 0; g < 512; ++g) s += Wlw[(size_t)g * 512 + h];
    wsum[h] = s;
  }
  __shared__ float red[256];
  float s = 0.f;
  for (int i = tid; i < 512; i += 256) s += blw[i];
  red[tid] = s;
  __syncthreads();
  for (int off = 128; off; off >>= 1) {
    if (tid < off) red[tid] += red[tid + off];
    __syncthreads();
  }
  if (tid == 0) { *bsumb = red[0]; *cnt = 0u; }
}

// ---------------------------------------------------------------------------
// One GRU layer, no LDS: thread = (j', b', ks). 6 coalesced weight float4 +
// 2 broadcast act/h float4 + 24 FMA per k-chunk, K-split reduced via shfl.
// Epilogue writes h and the router partial dots (h.wsum, h.Wsel_s) per jt.
__device__ __forceinline__ void do_layer(
    int tid, int j, int b, int ks, int jt, int lidx, int zeroH,
    const float* __restrict__ actbase, size_t actStride,
    const float* __restrict__ hprevbase,
    const float* __restrict__ Wih, const float* __restrict__ Whh,
    const float* __restrict__ bihL, const float* __restrict__ bhhL,
    const float* __restrict__ wsum, const float* __restrict__ Wsel,
    float* __restrict__ hout, float* __restrict__ hout2,
    float* __restrict__ dpart, float* __restrict__ epart) {
  const float* ar = actbase + (size_t)b * actStride + (ks << 7);
  const float* w0 = Wih + (size_t)j * KK + (ks << 7);
  const float* w1 = w0 + (size_t)HH * KK;
  const float* w2 = w1 + (size_t)HH * KK;
  const float* w3 = Whh + (size_t)j * KK + (ks << 7);
  const float* w4 = w3 + (size_t)HH * KK;
  const float* w5 = w4 + (size_t)HH * KK;
  float air = 0.f, aiz = 0.f, ain = 0.f, ahr = 0.f, ahz = 0.f, ahn = 0.f;
  if (!zeroH) {
    const float* hr = hprevbase + (size_t)b * HH + (ks << 7);
#pragma unroll 4
    for (int c = 0; c < 32; ++c) {
      float4 a4 = *(const float4*)(ar + (c << 2));
      float4 h4 = *(const float4*)(hr + (c << 2));
      float4 q0 = *(const float4*)(w0 + (c << 2));
      float4 q1 = *(const float4*)(w1 + (c << 2));
      float4 q2 = *(const float4*)(w2 + (c << 2));
      float4 q3 = *(const float4*)(w3 + (c << 2));
      float4 q4 = *(const float4*)(w4 + (c << 2));
      float4 q5 = *(const float4*)(w5 + (c << 2));
      air += a4.x * q0.x + a4.y * q0.y + a4.z * q0.z + a4.w * q0.w;
      aiz += a4.x * q1.x + a4.y * q1.y + a4.z * q1.z + a4.w * q1.w;
      ain += a4.x * q2.x + a4.y * q2.y + a4.z * q2.z + a4.w * q2.w;
      ahr += h4.x * q3.x + h4.y * q3.y + h4.z * q3.z + h4.w * q3.w;
      ahz += h4.x * q4.x + h4.y * q4.y + h4.z * q4.z + h4.w * q4.w;
      ahn += h4.x * q5.x + h4.y * q5.y + h4.z * q5.z + h4.w * q5.w;
    }
  } else {
#pragma unroll 4
    for (int c = 0; c < 32; ++c) {
      float4 a4 = *(const float4*)(ar + (c << 2));
      float4 q0 = *(const float4*)(w0 + (c << 2));
      float4 q1 = *(const float4*)(w1 + (c << 2));
      float4 q2 = *(const float4*)(w2 + (c << 2));
      air += a4.x * q0.x + a4.y * q0.y + a4.z * q0.z + a4.w * q0.w;
      aiz += a4.x * q1.x + a4.y * q1.y + a4.z * q1.z + a4.w * q1.w;
      ain += a4.x * q2.x + a4.y * q2.y + a4.z * q2.z + a4.w * q2.w;
    }
  }
  // full butterfly over the 4 K-split groups (lane bits 4,5) -> all lanes total
  air += __shfl_xor(air, 16); air += __shfl_xor(air, 32);
  aiz += __shfl_xor(aiz, 16); aiz += __shfl_xor(aiz, 32);
  ain += __shfl_xor(ain, 16); ain += __shfl_xor(ain, 32);
  ahr += __shfl_xor(ahr, 16); ahr += __shfl_xor(ahr, 32);
  ahz += __shfl_xor(ahz, 16); ahz += __shfl_xor(ahz, 32);
  ahn += __shfl_xor(ahn, 16); ahn += __shfl_xor(ahn, 32);

  float hp = zeroH ? 0.f : hprevbase[(size_t)b * HH + j];
  float rg = 1.f / (1.f + expf(-(air + bihL[j] + ahr + bhhL[j])));
  float zg = 1.f / (1.f + expf(-(aiz + bihL[j + 512] + ahz + bhhL[j + 512])));
  float ng = tanhf(ain + bihL[j + 1024] + rg * (ahn + bhhL[j + 1024]));
  float hv = (1.f - zg) * ng + zg * hp;
  if (ks == 0) {
    size_t oi = (size_t)b * HH + j;
    hout[oi] = hv;
    if (hout2) hout2[oi] = hv;
  }
  // router partials for next step: reduce over the 16 j' lanes
  float pd  = hv * wsum[j];
  float pe0 = hv * Wsel[j];
  float pe1 = hv * Wsel[1024 + j];
  float pe2 = hv * Wsel[2048 + j];
#pragma unroll
  for (int off = 1; off <= 8; off <<= 1) {
    pd  += __shfl_xor(pd, off);
    pe0 += __shfl_xor(pe0, off);
    pe1 += __shfl_xor(pe1, off);
    pe2 += __shfl_xor(pe2, off);
  }
  if ((tid & 63) == 0) {
    int row = lidx * 64 + b;
    dpart[row * 32 + jt] = pd;
    epart[(0 * 128 + row) * 32 + jt] = pe0;
    epart[(1 * 128 + row) * 32 + jt] = pe1;
    epart[(2 * 128 + row) * 32 + jt] = pe2;
  }
}

// ---------------------------------------------------------------------------
__global__ __launch_bounds__(NTHR, 2) void k_persist(
    const float* __restrict__ x,
    const float* __restrict__ Wih_first, const float* __restrict__ Wih_rest,
    const float* __restrict__ Whh,
    const float* __restrict__ bih, const float* __restrict__ bhh,
    const float* __restrict__ Wsel,
    const float* __restrict__ wsum, const float* __restrict__ bsumb,
    const float* __restrict__ xc,
    float* __restrict__ h0a, float* __restrict__ h0b,
    float* __restrict__ dpart, float* __restrict__ epart,
    float* __restrict__ out, unsigned* __restrict__ cnt) {
  __shared__ float d_sh[128];
  __shared__ float esh[384];
  __shared__ float lg[3];
  int tid = threadIdx.x, bid = blockIdx.x;
  // XCD-aware tile map: bid&7 ~ XCD; each XCD gets a 4-jt group (L2-resident)
  int xcd = bid & 7, s8 = bid >> 3;
  int jt = (xcd << 2) | (s8 & 3);   // 0..31, 16 j each
  int bt = s8 >> 2;                 // 0..7, 8 b each
  int jl = tid & 15, ks = (tid >> 4) & 3, bl = tid >> 6;
  int j = (jt << 4) + jl;
  int b = (bt << 3) + bl;

  float p0 = PEN, p1 = 1.f, p2 = 1.f;
  int cur = 0;
  unsigned nbar = 0;
  float bs = *bsumb;

  for (int t = 0; t < TT; ++t) {
    float* hw = (t & 1) ? h0b : h0a;
    const float* hp = (t & 1) ? h0a : h0b;

    if (t > 0) {
      // ---- router from partial arrays (redundant per block, deterministic) ----
      const float* base = (tid < 128) ? (dpart + tid * 32) : (epart + (size_t)(tid - 128) * 32);
      float val = 0.f;
#pragma unroll
      for (int c = 0; c < 8; ++c) {
        float4 v4 = *(const float4*)(base + (c << 2));
        val += v4.x + v4.y + v4.z + v4.w;
      }
      if (tid < 128) d_sh[tid] = val;
      __syncthreads();
      if (tid >= 128) {
        int idx = tid - 128;          // idx = s*128 + l*64 + b
        esh[idx] = (d_sh[idx & 127] + bs) * val;
      }
      __syncthreads();
      if (tid < 192) {
        int seg = tid >> 6, i = tid & 63;
        float v = esh[seg * 128 + i] + esh[seg * 128 + 64 + i];
#pragma unroll
        for (int off = 1; off <= 32; off <<= 1) v += __shfl_xor(v, off);
        if (i == 0) lg[seg] = v + xc[t * 4 + seg];
      }
      __syncthreads();
      float l0 = lg[0], l1 = lg[1], l2 = lg[2];
      float m = fmaxf(l0, fmaxf(l1, l2));
      float q0 = expf(l0 - m), q1 = expf(l1 - m), q2 = expf(l2 - m);
      float Z = q0 + q1 + q2;
      float pr0 = q0 / Z * p0, pr1 = q1 / Z * p1, pr2 = q2 / Z * p2;
      cur = 0;
      float best = pr0;
      if (pr1 > best) { best = pr1; cur = 1; }
      if (pr2 > best) { best = pr2; cur = 2; }
      p0 *= (cur == 0) ? PEN : 1.f;
      p1 *= (cur == 1) ? PEN : 1.f;
      p2 *= (cur == 2) ? PEN : 1.f;
      float mx = fmaxf(p0, fmaxf(p1, p2));
      p0 /= mx; p1 /= mx; p2 /= mx;
    }

    // ---- layer 0 ----
    do_layer(tid, j, b, ks, jt, 0, (t == 0),
             x + (size_t)t * KK, (size_t)TT * KK, hp,
             Wih_first + (size_t)cur * WSTRIDE,
             Whh + (size_t)(cur * 2 + 0) * WSTRIDE,
             bih + (size_t)(cur * 2 + 0) * G3, bhh + (size_t)(cur * 2 + 0) * G3,
             wsum, Wsel, hw, nullptr, dpart, epart);
    gbar(cnt, (++nbar) * NBLK);

    // ---- layer 1 ----
    const float* h1p = (t == 0) ? nullptr : (out + (size_t)(t - 1) * BB * HH);
    float* o2 = (t == TT - 1) ? (out + (size_t)TT * BB * HH) : nullptr;
    do_layer(tid, j, b, ks, jt, 1, (t == 0),
             hw, (size_t)HH, h1p,
             Wih_rest + (size_t)cur * WSTRIDE,
             Whh + (size_t)(cur * 2 + 1) * WSTRIDE,
             bih + (size_t)(cur * 2 + 1) * G3, bhh + (size_t)(cur * 2 + 1) * G3,
             wsum, Wsel, out + (size_t)t * BB * HH, o2, dpart, epart);
    gbar(cnt, (++nbar) * NBLK);
  }
}

// ---------------------------------------------------------------------------
extern "C" void kernel_launch(void* const* d_in, const int* in_sizes, int n_in,
                              void* d_out, int out_size, void* d_ws, size_t ws_size,
                              hipStream_t stream) {
  const float* x         = (const float*)d_in[0];
  const float* Wih_first = (const float*)d_in[1];
  const float* Wih_rest  = (const float*)d_in[2];
  const float* Whh       = (const float*)d_in[3];
  const float* bih       = (const float*)d_in[4];
  const float* bhh       = (const float*)d_in[5];
  const float* Wlw       = (const float*)d_in[6];
  const float* blw       = (const float*)d_in[7];
  const float* Wsel      = (const float*)d_in[8];
  const float* bsel      = (const float*)d_in[9];
  float* out = (float*)d_out;
  float* ws  = (float*)d_ws;

  float* h0a   = ws;                    // 64*512
  float* h0b   = h0a + BB * HH;         // 64*512
  float* xc    = h0b + BB * HH;         // 512*4
  float* wsum  = xc + TT * 4;           // 512
  float* bsumb = wsum + HH;             // 1
  float* dpart = bsumb + 1;             // 2*64*32 = 4096
  float* epart = dpart + 4096;          // 3*2*64*32 = 12288
  unsigned* cnt = (unsigned*)(epart + 12288);

  k_pre_xc<<<dim3(TT), 256, 0, stream>>>(x, Wsel, bsel, xc);
  k_pre_misc<<<dim3(1), 256, 0, stream>>>(Wlw, blw, wsum, bsumb, cnt);
  k_persist<<<dim3(NBLK), NTHR, 0, stream>>>(x, Wih_first, Wih_rest, Whh, bih, bhh,
                                             Wsel, wsum, bsumb, xc,
                                             h0a, h0b, dpart, epart, out, cnt);
}

// Round 4
// 49396.637 us; speedup vs baseline: 1.6191x; 1.6191x over previous
//
#include <hip/hip_runtime.h>
#include <math.h>

#define BB 64
#define TT 512
#define HH 512
#define KK 512
#define G3 1536
#define PEN 0.7f
#define NBLK 256
#define NTHR 512
#define SLAB 32768               // 64*512 floats (one transposed activation slab)
#define WSTRIDE ((size_t)(G3 * KK))

// ---------------------------------------------------------------------------
// grid barrier: release-RMW arrival, relaxed spin, one acquire at exit.
__device__ __forceinline__ void gbar(unsigned* cnt, unsigned target) {
  __syncthreads();
  if (threadIdx.x == 0) {
    __hip_atomic_fetch_add(cnt, 1u, __ATOMIC_RELEASE, __HIP_MEMORY_SCOPE_AGENT);
    while (__hip_atomic_load(cnt, __ATOMIC_RELAXED, __HIP_MEMORY_SCOPE_AGENT) < target)
      __builtin_amdgcn_s_sleep(2);
    (void)__hip_atomic_load(cnt, __ATOMIC_ACQUIRE, __HIP_MEMORY_SCOPE_AGENT);
  }
  __syncthreads();
}

// ---------------------------------------------------------------------------
// pre 1: xc[t][s] = sum_b x[b,t,:] . Wsel[s,512:] + B*bsel[s]
__global__ void k_pre_xc(const float* __restrict__ x, const float* __restrict__ Wsel,
                         const float* __restrict__ bsel, float* __restrict__ xc) {
  int t = blockIdx.x, tid = threadIdx.x;
  __shared__ float xs[512];
  __shared__ float a0[256], a1[256], a2[256];
  for (int i = tid; i < 512; i += 256) {
    float s = 0.f;
    const float* px = x + (size_t)t * KK + i;
    for (int b = 0; b < BB; ++b) s += px[(size_t)b * TT * KK];
    xs[i] = s;
  }
  __syncthreads();
  float c0 = 0.f, c1 = 0.f, c2 = 0.f;
  for (int i = tid; i < 512; i += 256) {
    float v = xs[i];
    c0 += v * Wsel[512 + i];
    c1 += v * Wsel[1024 + 512 + i];
    c2 += v * Wsel[2048 + 512 + i];
  }
  a0[tid] = c0; a1[tid] = c1; a2[tid] = c2;
  __syncthreads();
  for (int off = 128; off; off >>= 1) {
    if (tid < off) { a0[tid] += a0[tid + off]; a1[tid] += a1[tid + off]; a2[tid] += a2[tid + off]; }
    __syncthreads();
  }
  if (tid == 0) {
    xc[t * 4 + 0] = a0[0] + 64.f * bsel[0];
    xc[t * 4 + 1] = a1[0] + 64.f * bsel[1];
    xc[t * 4 + 2] = a2[0] + 64.f * bsel[2];
  }
}

// pre 2: wsum/bsum, zero t=0 hidden slabs, transpose x[:,0,:], init flags
__global__ void k_pre_misc(const float* __restrict__ Wlw, const float* __restrict__ blw,
                           const float* __restrict__ x,
                           float* __restrict__ wsum, float* __restrict__ bsumb,
                           float* __restrict__ xT0,
                           float* __restrict__ h0T0, float* __restrict__ h1T0,
                           int* __restrict__ curw, unsigned* __restrict__ cnt) {
  int gtid = blockIdx.x * 256 + threadIdx.x;        // 64 blocks * 256
  for (int i = gtid; i < SLAB; i += 64 * 256) { h0T0[i] = 0.f; h1T0[i] = 0.f; }
  for (int i = gtid; i < SLAB; i += 64 * 256) {
    int b = i >> 9, k = i & 511;
    xT0[(k >> 2) * 256 + b * 4 + (k & 3)] = x[(size_t)b * TT * KK + k];
  }
  if (blockIdx.x == 0) {
    int tid = threadIdx.x;
    for (int h = tid; h < 512; h += 256) {
      float s = 0.f;
      for (int g = 0; g < 512; ++g) s += Wlw[(size_t)g * 512 + h];
      wsum[h] = s;
    }
    __shared__ float red[256];
    float s = 0.f;
    for (int i = tid; i < 512; i += 256) s += blw[i];
    red[tid] = s;
    __syncthreads();
    for (int off = 128; off; off >>= 1) {
      if (tid < off) red[tid] += red[tid + off];
      __syncthreads();
    }
    if (tid == 0) { *bsumb = red[0]; *curw = 0; *cnt = 0u; }
  }
}

// ---------------------------------------------------------------------------
// One GRU layer. wave = (K/8 slice) x (both j of this block); lane = b.
// Weights: wave-uniform addresses (scalar/broadcast loads, ~1 line per load).
// Acts: transposed-packed hT4[k/4][b] -> lane-b float4 loads fully coalesced.
__device__ __forceinline__ void do_layer(
    int tid, int b, int k0, int j0, int lidx, int bid,
    const float* __restrict__ act, const float* __restrict__ hTprev,
    const float* __restrict__ Wih, const float* __restrict__ Whh,
    const float* __restrict__ bihL, const float* __restrict__ bhhL,
    const float* __restrict__ wsum, const float* __restrict__ Wsel,
    float* __restrict__ houtT, float* __restrict__ houtN, float* __restrict__ houtN2,
    float* __restrict__ dpart, float* __restrict__ epart,
    float* red, float* r2) {
  int w = tid >> 6;
  const float* a4p = act + (k0 >> 2) * 256 + b * 4;
  const float* h4p = hTprev + (k0 >> 2) * 256 + b * 4;
  const float* wi0r = Wih + (size_t)(j0 + 0) * KK + k0;
  const float* wi1r = Wih + (size_t)(j0 + 1) * KK + k0;
  const float* wi0z = Wih + (size_t)(512 + j0 + 0) * KK + k0;
  const float* wi1z = Wih + (size_t)(512 + j0 + 1) * KK + k0;
  const float* wi0n = Wih + (size_t)(1024 + j0 + 0) * KK + k0;
  const float* wi1n = Wih + (size_t)(1024 + j0 + 1) * KK + k0;
  const float* wh0r = Whh + (size_t)(j0 + 0) * KK + k0;
  const float* wh1r = Whh + (size_t)(j0 + 1) * KK + k0;
  const float* wh0z = Whh + (size_t)(512 + j0 + 0) * KK + k0;
  const float* wh1z = Whh + (size_t)(512 + j0 + 1) * KK + k0;
  const float* wh0n = Whh + (size_t)(1024 + j0 + 0) * KK + k0;
  const float* wh1n = Whh + (size_t)(1024 + j0 + 1) * KK + k0;
  float ai0r = 0.f, ai1r = 0.f, ai0z = 0.f, ai1z = 0.f, ai0n = 0.f, ai1n = 0.f;
  float ah0r = 0.f, ah1r = 0.f, ah0z = 0.f, ah1z = 0.f, ah0n = 0.f, ah1n = 0.f;
#pragma unroll 4
  for (int c = 0; c < 16; ++c) {
    float4 a4 = *(const float4*)(a4p + c * 256);
    float4 h4 = *(const float4*)(h4p + c * 256);
    float4 q;
#define DOT(acc, ptr, vv) q = *(const float4*)((ptr) + c * 4); \
    acc += vv.x * q.x + vv.y * q.y + vv.z * q.z + vv.w * q.w;
    DOT(ai0r, wi0r, a4) DOT(ai1r, wi1r, a4)
    DOT(ai0z, wi0z, a4) DOT(ai1z, wi1z, a4)
    DOT(ai0n, wi0n, a4) DOT(ai1n, wi1n, a4)
    DOT(ah0r, wh0r, h4) DOT(ah1r, wh1r, h4)
    DOT(ah0z, wh0z, h4) DOT(ah1z, wh1z, h4)
    DOT(ah0n, wh0n, h4) DOT(ah1n, wh1n, h4)
#undef DOT
  }
  int base = (w * 12) * 64 + b;
  red[base + 0 * 64] = ai0r; red[base + 1 * 64] = ai0z; red[base + 2 * 64] = ai0n;
  red[base + 3 * 64] = ah0r; red[base + 4 * 64] = ah0z; red[base + 5 * 64] = ah0n;
  red[base + 6 * 64] = ai1r; red[base + 7 * 64] = ai1z; red[base + 8 * 64] = ai1n;
  red[base + 9 * 64] = ah1r; red[base + 10 * 64] = ah1z; red[base + 11 * 64] = ah1n;
  __syncthreads();
  if (tid < 128) {
    int bb = tid & 63, jl = tid >> 6;
    int j = j0 + jl;
    float sir = 0.f, siz = 0.f, sinn = 0.f, shr = 0.f, shz = 0.f, shn = 0.f;
#pragma unroll
    for (int ww = 0; ww < 8; ++ww) {
      int o = (ww * 12 + jl * 6) * 64 + bb;
      sir += red[o]; siz += red[o + 64]; sinn += red[o + 128];
      shr += red[o + 192]; shz += red[o + 256]; shn += red[o + 320];
    }
    float air = sir + bihL[j],        ahr = shr + bhhL[j];
    float aiz = siz + bihL[j + 512],  ahz = shz + bhhL[j + 512];
    float ain = sinn + bihL[j + 1024], ahn = shn + bhhL[j + 1024];
    float rg = 1.f / (1.f + expf(-(air + ahr)));
    float zg = 1.f / (1.f + expf(-(aiz + ahz)));
    float ng = tanhf(ain + rg * ahn);
    float hp = hTprev[(j >> 2) * 256 + bb * 4 + (j & 3)];
    float hv = (1.f - zg) * ng + zg * hp;
    houtT[(j >> 2) * 256 + bb * 4 + (j & 3)] = hv;
    if (houtN) houtN[(size_t)bb * HH + j] = hv;
    if (houtN2) houtN2[(size_t)bb * HH + j] = hv;
    r2[jl * 256 + 0 * 64 + bb] = hv * wsum[j];
    r2[jl * 256 + 1 * 64 + bb] = hv * Wsel[j];
    r2[jl * 256 + 2 * 64 + bb] = hv * Wsel[1024 + j];
    r2[jl * 256 + 3 * 64 + bb] = hv * Wsel[2048 + j];
  }
  __syncthreads();
  if (tid < 64) {
    int row = lidx * 64 + tid;
    dpart[(size_t)row * NBLK + bid]                 = r2[tid]       + r2[256 + tid];
    epart[((size_t)0 * 128 + row) * NBLK + bid]     = r2[64 + tid]  + r2[256 + 64 + tid];
    epart[((size_t)1 * 128 + row) * NBLK + bid]     = r2[128 + tid] + r2[256 + 128 + tid];
    epart[((size_t)2 * 128 + row) * NBLK + bid]     = r2[192 + tid] + r2[256 + 192 + tid];
  }
}

// ---------------------------------------------------------------------------
__global__ __launch_bounds__(NTHR, 2) void k_persist(
    const float* __restrict__ x,
    const float* __restrict__ Wih_first, const float* __restrict__ Wih_rest,
    const float* __restrict__ Whh,
    const float* __restrict__ bih, const float* __restrict__ bhh,
    const float* __restrict__ Wsel,
    const float* __restrict__ wsum, const float* __restrict__ bsumb,
    const float* __restrict__ xc,
    float* __restrict__ xT, float* __restrict__ h0T, float* __restrict__ h1T,
    float* __restrict__ dpart, float* __restrict__ epart,
    float* __restrict__ out, int* __restrict__ curw, unsigned* __restrict__ cnt) {
  __shared__ float red[8 * 12 * 64];   // 24 KB wave partials / router scratch
  __shared__ float r2[2 * 4 * 64];     // 2 KB j-pair reduce
  int tid = threadIdx.x, bid = blockIdx.x;
  int b = tid & 63;
  int k0 = __builtin_amdgcn_readfirstlane(((int)threadIdx.x >> 6) << 6);
  int j0 = bid * 2;
  float p0 = PEN, p1 = 1.f, p2 = 1.f;  // penalty state (only block0/thread0's matters)
  int cur = 0;
  unsigned nbar = 0;
  float bs = *bsumb;

  for (int t = 0; t < TT; ++t) {
    int pr = t & 1;
    const float* xTc = xT + pr * SLAB;
    float* xTn = xT + (pr ^ 1) * SLAB;
    const float* h0Tp = h0T + pr * SLAB;
    float* h0Tn = h0T + (pr ^ 1) * SLAB;
    const float* h1Tp = h1T + pr * SLAB;
    float* h1Tn = h1T + (pr ^ 1) * SLAB;

    if (t > 0) {
      // ---- router: block 0 only; reads the 4 partial arrays (coalesced) ----
      if (bid == 0) {
        int row = tid >> 2, seg = tid & 3;
        const float* dp = dpart + (size_t)row * NBLK + seg * 64;
        float sd = 0.f;
#pragma unroll
        for (int c = 0; c < 16; ++c) {
          float4 v = *(const float4*)(dp + c * 4);
          sd += v.x + v.y + v.z + v.w;
        }
        sd += __shfl_xor(sd, 1); sd += __shfl_xor(sd, 2);
        float se0 = 0.f, se1 = 0.f, se2 = 0.f;
        {
          const float* ep = epart + (size_t)row * NBLK + seg * 64;
#pragma unroll
          for (int c = 0; c < 16; ++c) {
            float4 v = *(const float4*)(ep + c * 4);
            se0 += v.x + v.y + v.z + v.w;
          }
          ep = epart + ((size_t)128 + row) * NBLK + seg * 64;
#pragma unroll
          for (int c = 0; c < 16; ++c) {
            float4 v = *(const float4*)(ep + c * 4);
            se1 += v.x + v.y + v.z + v.w;
          }
          ep = epart + ((size_t)256 + row) * NBLK + seg * 64;
#pragma unroll
          for (int c = 0; c < 16; ++c) {
            float4 v = *(const float4*)(ep + c * 4);
            se2 += v.x + v.y + v.z + v.w;
          }
        }
        se0 += __shfl_xor(se0, 1); se0 += __shfl_xor(se0, 2);
        se1 += __shfl_xor(se1, 1); se1 += __shfl_xor(se1, 2);
        se2 += __shfl_xor(se2, 1); se2 += __shfl_xor(se2, 2);
        float le = sd + bs;
        float q0 = le * se0, q1 = le * se1, q2 = le * se2;
        if (seg != 0) { q0 = 0.f; q1 = 0.f; q2 = 0.f; }
#pragma unroll
        for (int off = 1; off < 64; off <<= 1) {
          q0 += __shfl_xor(q0, off);
          q1 += __shfl_xor(q1, off);
          q2 += __shfl_xor(q2, off);
        }
        if ((tid & 63) == 0) {
          red[(tid >> 6) * 3 + 0] = q0;
          red[(tid >> 6) * 3 + 1] = q1;
          red[(tid >> 6) * 3 + 2] = q2;
        }
        __syncthreads();
        if (tid == 0) {
          float l0 = xc[t * 4 + 0], l1 = xc[t * 4 + 1], l2 = xc[t * 4 + 2];
#pragma unroll
          for (int ww = 0; ww < 8; ++ww) {
            l0 += red[ww * 3 + 0]; l1 += red[ww * 3 + 1]; l2 += red[ww * 3 + 2];
          }
          float m = fmaxf(l0, fmaxf(l1, l2));
          float e0 = expf(l0 - m), e1 = expf(l1 - m), e2 = expf(l2 - m);
          float Z = e0 + e1 + e2;
          float w0 = e0 / Z * p0, w1 = e1 / Z * p1, w2 = e2 / Z * p2;
          int c = 0; float bestv = w0;
          if (w1 > bestv) { bestv = w1; c = 1; }
          if (w2 > bestv) { bestv = w2; c = 2; }
          p0 *= (c == 0) ? PEN : 1.f;
          p1 *= (c == 1) ? PEN : 1.f;
          p2 *= (c == 2) ? PEN : 1.f;
          float mx = fmaxf(p0, fmaxf(p1, p2));
          p0 /= mx; p1 /= mx; p2 /= mx;
          *curw = c;
        }
      }
      gbar(cnt, (++nbar) * NBLK);
      cur = __hip_atomic_load(curw, __ATOMIC_RELAXED, __HIP_MEMORY_SCOPE_AGENT);
    }

    // ---- transpose x[:, t+1, :] one step ahead (consumed after >=2 barriers) ----
    if (t + 1 < TT && tid < 128) {
      int idx = bid * 128 + tid;
      int b2 = idx >> 9, k = idx & 511;
      xTn[(k >> 2) * 256 + b2 * 4 + (k & 3)] =
          x[(size_t)b2 * TT * KK + (size_t)(t + 1) * KK + k];
    }

    // ---- layer 0 ----
    do_layer(tid, b, k0, j0, 0, bid, xTc, h0Tp,
             Wih_first + (size_t)cur * WSTRIDE,
             Whh + (size_t)(cur * 2 + 0) * WSTRIDE,
             bih + (size_t)(cur * 2 + 0) * G3, bhh + (size_t)(cur * 2 + 0) * G3,
             wsum, Wsel, h0Tn, nullptr, nullptr, dpart, epart, red, r2);
    gbar(cnt, (++nbar) * NBLK);

    // ---- layer 1 ----
    float* o2 = (t == TT - 1) ? (out + (size_t)TT * BB * HH) : nullptr;
    do_layer(tid, b, k0, j0, 1, bid, h0Tn, h1Tp,
             Wih_rest + (size_t)cur * WSTRIDE,
             Whh + (size_t)(cur * 2 + 1) * WSTRIDE,
             bih + (size_t)(cur * 2 + 1) * G3, bhh + (size_t)(cur * 2 + 1) * G3,
             wsum, Wsel, h1Tn, out + (size_t)t * BB * HH, o2, dpart, epart, red, r2);
    gbar(cnt, (++nbar) * NBLK);
  }
}

// ---------------------------------------------------------------------------
extern "C" void kernel_launch(void* const* d_in, const int* in_sizes, int n_in,
                              void* d_out, int out_size, void* d_ws, size_t ws_size,
                              hipStream_t stream) {
  const float* x         = (const float*)d_in[0];
  const float* Wih_first = (const float*)d_in[1];
  const float* Wih_rest  = (const float*)d_in[2];
  const float* Whh       = (const float*)d_in[3];
  const float* bih       = (const float*)d_in[4];
  const float* bhh       = (const float*)d_in[5];
  const float* Wlw       = (const float*)d_in[6];
  const float* blw       = (const float*)d_in[7];
  const float* Wsel      = (const float*)d_in[8];
  const float* bsel      = (const float*)d_in[9];
  float* out = (float*)d_out;
  float* ws  = (float*)d_ws;

  float* xT    = ws;                       // 2 * 32768
  float* h0T   = xT + 2 * SLAB;            // 2 * 32768
  float* h1T   = h0T + 2 * SLAB;           // 2 * 32768
  float* dpart = h1T + 2 * SLAB;           // 128 * 256
  float* epart = dpart + 128 * NBLK;       // 3 * 128 * 256
  float* xc    = epart + 3 * 128 * NBLK;   // 512 * 4
  float* wsum  = xc + TT * 4;              // 512
  float* bsumb = wsum + HH;                // 1
  int*   curw  = (int*)(bsumb + 1);
  unsigned* cnt = (unsigned*)(curw + 1);

  k_pre_xc<<<dim3(TT), 256, 0, stream>>>(x, Wsel, bsel, xc);
  k_pre_misc<<<dim3(64), 256, 0, stream>>>(Wlw, blw, x, wsum, bsumb,
                                           xT, h0T, h1T, curw, cnt);
  k_persist<<<dim3(NBLK), NTHR, 0, stream>>>(x, Wih_first, Wih_rest, Whh, bih, bhh,
                                             Wsel, wsum, bsumb, xc,
                                             xT, h0T, h1T, dpart, epart,
                                             out, curw, cnt);
}

// Round 5
// 32611.105 us; speedup vs baseline: 2.4525x; 1.5147x over previous
//
#include <hip/hip_runtime.h>
#include <math.h>

#define BB 64
#define TT 512
#define HH 512
#define KK 512
#define G3 1536
#define PEN 0.7f
#define NBLK 256
#define NTHR 512
#define SLAB 32768               // 64*512 floats (one transposed activation slab)
#define WSTRIDE ((size_t)(G3 * KK))

__device__ __forceinline__ unsigned ld_rlx(const unsigned* p) {
  return __hip_atomic_load(p, __ATOMIC_RELAXED, __HIP_MEMORY_SCOPE_AGENT);
}
__device__ __forceinline__ unsigned umin2(unsigned a, unsigned b) { return a < b ? a : b; }

// ---------------------------------------------------------------------------
// pre 1: xc[t][s] = sum_b x[b,t,:] . Wsel[s,512:] + B*bsel[s]
__global__ void k_pre_xc(const float* __restrict__ x, const float* __restrict__ Wsel,
                         const float* __restrict__ bsel, float* __restrict__ xc) {
  int t = blockIdx.x, tid = threadIdx.x;
  __shared__ float xs[512];
  __shared__ float a0[256], a1[256], a2[256];
  for (int i = tid; i < 512; i += 256) {
    float s = 0.f;
    const float* px = x + (size_t)t * KK + i;
    for (int b = 0; b < BB; ++b) s += px[(size_t)b * TT * KK];
    xs[i] = s;
  }
  __syncthreads();
  float c0 = 0.f, c1 = 0.f, c2 = 0.f;
  for (int i = tid; i < 512; i += 256) {
    float v = xs[i];
    c0 += v * Wsel[512 + i];
    c1 += v * Wsel[1024 + 512 + i];
    c2 += v * Wsel[2048 + 512 + i];
  }
  a0[tid] = c0; a1[tid] = c1; a2[tid] = c2;
  __syncthreads();
  for (int off = 128; off; off >>= 1) {
    if (tid < off) { a0[tid] += a0[tid + off]; a1[tid] += a1[tid + off]; a2[tid] += a2[tid + off]; }
    __syncthreads();
  }
  if (tid == 0) {
    xc[t * 4 + 0] = a0[0] + 64.f * bsel[0];
    xc[t * 4 + 1] = a1[0] + 64.f * bsel[1];
    xc[t * 4 + 2] = a2[0] + 64.f * bsel[2];
  }
}

// pre 2: wsum/bsum, zero t=0 hidden slabs, transpose x[:,0,:], init sync words
__global__ void k_pre_misc(const float* __restrict__ Wlw, const float* __restrict__ blw,
                           const float* __restrict__ x,
                           float* __restrict__ wsum, float* __restrict__ bsumb,
                           float* __restrict__ xT0,
                           float* __restrict__ h0T0, float* __restrict__ h1T0,
                           unsigned* __restrict__ flags, unsigned* __restrict__ relw,
                           unsigned* __restrict__ curk) {
  int gtid = blockIdx.x * 256 + threadIdx.x;        // 64 blocks * 256
  for (int i = gtid; i < SLAB; i += 64 * 256) { h0T0[i] = 0.f; h1T0[i] = 0.f; }
  for (int i = gtid; i < SLAB; i += 64 * 256) {
    int b = i >> 9, k = i & 511;
    xT0[(k >> 2) * 256 + b * 4 + (k & 3)] = x[(size_t)b * TT * KK + k];
  }
  if (blockIdx.x == 0) {
    int tid = threadIdx.x;
    if (tid < 256) flags[tid] = 0u;
    for (int h = tid; h < 512; h += 256) {
      float s = 0.f;
      for (int g = 0; g < 512; ++g) s += Wlw[(size_t)g * 512 + h];
      wsum[h] = s;
    }
    __shared__ float red[256];
    float s = 0.f;
    for (int i = tid; i < 512; i += 256) s += blw[i];
    red[tid] = s;
    __syncthreads();
    for (int off = 128; off; off >>= 1) {
      if (tid < off) red[tid] += red[tid + off];
      __syncthreads();
    }
    if (tid == 0) { *bsumb = red[0]; *relw = 0u; *curk = 0u; }
  }
}

// ---------------------------------------------------------------------------
// One GRU layer. wave = (K/8 slice) x (both j of this block); lane = b.
// Weights: wave-uniform addresses (scalar/broadcast loads). Acts: transposed
// hT4[k/4][b] -> lane-b float4 loads fully coalesced.
__device__ __forceinline__ void do_layer(
    int tid, int b, int k0, int j0, int lidx, int bid,
    const float* __restrict__ act, const float* __restrict__ hTprev,
    const float* __restrict__ Wih, const float* __restrict__ Whh,
    const float* __restrict__ bihL, const float* __restrict__ bhhL,
    const float* __restrict__ wsum, const float* __restrict__ Wsel,
    float* __restrict__ houtT, float* __restrict__ houtN, float* __restrict__ houtN2,
    float* __restrict__ part, float* red, float* r2) {
  int w = tid >> 6;
  const float* a4p = act + (k0 >> 2) * 256 + b * 4;
  const float* h4p = hTprev + (k0 >> 2) * 256 + b * 4;
  const float* wi0r = Wih + (size_t)(j0 + 0) * KK + k0;
  const float* wi1r = Wih + (size_t)(j0 + 1) * KK + k0;
  const float* wi0z = Wih + (size_t)(512 + j0 + 0) * KK + k0;
  const float* wi1z = Wih + (size_t)(512 + j0 + 1) * KK + k0;
  const float* wi0n = Wih + (size_t)(1024 + j0 + 0) * KK + k0;
  const float* wi1n = Wih + (size_t)(1024 + j0 + 1) * KK + k0;
  const float* wh0r = Whh + (size_t)(j0 + 0) * KK + k0;
  const float* wh1r = Whh + (size_t)(j0 + 1) * KK + k0;
  const float* wh0z = Whh + (size_t)(512 + j0 + 0) * KK + k0;
  const float* wh1z = Whh + (size_t)(512 + j0 + 1) * KK + k0;
  const float* wh0n = Whh + (size_t)(1024 + j0 + 0) * KK + k0;
  const float* wh1n = Whh + (size_t)(1024 + j0 + 1) * KK + k0;
  float ai0r = 0.f, ai1r = 0.f, ai0z = 0.f, ai1z = 0.f, ai0n = 0.f, ai1n = 0.f;
  float ah0r = 0.f, ah1r = 0.f, ah0z = 0.f, ah1z = 0.f, ah0n = 0.f, ah1n = 0.f;
#pragma unroll 4
  for (int c = 0; c < 16; ++c) {
    float4 a4 = *(const float4*)(a4p + c * 256);
    float4 h4 = *(const float4*)(h4p + c * 256);
    float4 q;
#define DOT(acc, ptr, vv) q = *(const float4*)((ptr) + c * 4); \
    acc += vv.x * q.x + vv.y * q.y + vv.z * q.z + vv.w * q.w;
    DOT(ai0r, wi0r, a4) DOT(ai1r, wi1r, a4)
    DOT(ai0z, wi0z, a4) DOT(ai1z, wi1z, a4)
    DOT(ai0n, wi0n, a4) DOT(ai1n, wi1n, a4)
    DOT(ah0r, wh0r, h4) DOT(ah1r, wh1r, h4)
    DOT(ah0z, wh0z, h4) DOT(ah1z, wh1z, h4)
    DOT(ah0n, wh0n, h4) DOT(ah1n, wh1n, h4)
#undef DOT
  }
  int base = (w * 12) * 64 + b;
  red[base + 0 * 64] = ai0r; red[base + 1 * 64] = ai0z; red[base + 2 * 64] = ai0n;
  red[base + 3 * 64] = ah0r; red[base + 4 * 64] = ah0z; red[base + 5 * 64] = ah0n;
  red[base + 6 * 64] = ai1r; red[base + 7 * 64] = ai1z; red[base + 8 * 64] = ai1n;
  red[base + 9 * 64] = ah1r; red[base + 10 * 64] = ah1z; red[base + 11 * 64] = ah1n;
  __syncthreads();
  if (tid < 128) {
    int bb = tid & 63, jl = tid >> 6;
    int j = j0 + jl;
    float sir = 0.f, siz = 0.f, sinn = 0.f, shr = 0.f, shz = 0.f, shn = 0.f;
#pragma unroll
    for (int ww = 0; ww < 8; ++ww) {
      int o = (ww * 12 + jl * 6) * 64 + bb;
      sir += red[o]; siz += red[o + 64]; sinn += red[o + 128];
      shr += red[o + 192]; shz += red[o + 256]; shn += red[o + 320];
    }
    float air = sir + bihL[j],         ahr = shr + bhhL[j];
    float aiz = siz + bihL[j + 512],   ahz = shz + bhhL[j + 512];
    float ain = sinn + bihL[j + 1024], ahn = shn + bhhL[j + 1024];
    float rg = 1.f / (1.f + expf(-(air + ahr)));
    float zg = 1.f / (1.f + expf(-(aiz + ahz)));
    float ng = tanhf(ain + rg * ahn);
    float hp = hTprev[(j >> 2) * 256 + bb * 4 + (j & 3)];
    float hv = (1.f - zg) * ng + zg * hp;
    houtT[(j >> 2) * 256 + bb * 4 + (j & 3)] = hv;
    if (houtN) houtN[(size_t)bb * HH + j] = hv;
    if (houtN2) houtN2[(size_t)bb * HH + j] = hv;
    r2[jl * 256 + 0 * 64 + bb] = hv * wsum[j];
    r2[jl * 256 + 1 * 64 + bb] = hv * Wsel[j];
    r2[jl * 256 + 2 * 64 + bb] = hv * Wsel[1024 + j];
    r2[jl * 256 + 3 * 64 + bb] = hv * Wsel[2048 + j];
  }
  __syncthreads();
  if (tid < 64) {
    // part[bid][512]: [0..127]=d rows (l*64+b), [128..255]=e0, [256..383]=e1, [384..511]=e2
    float* pb = part + (size_t)bid * 512;
    pb[lidx * 64 + tid]       = r2[tid]       + r2[256 + tid];
    pb[128 + lidx * 64 + tid] = r2[64 + tid]  + r2[256 + 64 + tid];
    pb[256 + lidx * 64 + tid] = r2[128 + tid] + r2[256 + 128 + tid];
    pb[384 + lidx * 64 + tid] = r2[192 + tid] + r2[256 + 192 + tid];
  }
}

// ---------------------------------------------------------------------------
__global__ __launch_bounds__(NTHR, 2) void k_persist(
    const float* __restrict__ x,
    const float* __restrict__ Wih_first, const float* __restrict__ Wih_rest,
    const float* __restrict__ Whh,
    const float* __restrict__ bih, const float* __restrict__ bhh,
    const float* __restrict__ Wsel,
    const float* __restrict__ wsum, const float* __restrict__ bsumb,
    const float* __restrict__ xc,
    float* __restrict__ xT, float* __restrict__ h0T, float* __restrict__ h1T,
    float* __restrict__ part, float* __restrict__ out,
    unsigned* __restrict__ flags, unsigned* __restrict__ relw,
    unsigned* __restrict__ curk) {
  __shared__ float red[8 * 12 * 64];   // 24 KB wave partials / router scratch
  __shared__ float r2[2 * 4 * 64];     // j-pair reduce / router wave sums
  __shared__ int curs;
  int tid = threadIdx.x, bid = blockIdx.x;
  int b = tid & 63;
  int k0 = __builtin_amdgcn_readfirstlane(((int)threadIdx.x >> 6) << 6);
  int j0 = bid * 2;
  float p0 = PEN, p1 = 1.f, p2 = 1.f;  // penalty state (only block0/tid0's matters)
  int cur = 0;
  float bs = *bsumb;

  for (int t = 0; t < TT; ++t) {
    int pr = t & 1;
    const float* xTc = xT + pr * SLAB;
    float* xTn = xT + (pr ^ 1) * SLAB;
    const float* h0Tp = h0T + pr * SLAB;
    float* h0Tn = h0T + (pr ^ 1) * SLAB;
    const float* h1Tp = h1T + pr * SLAB;
    float* h1Tn = h1T + (pr ^ 1) * SLAB;

    if (t > 0) {
      // ---- router fan-in/fan-out: block 0 waits for layer-1 flags (epoch 2t),
      // computes cur, publishes (t<<2)|cur; others poll that word only. ----
      if (bid == 0) {
        unsigned ep = 2u * (unsigned)t;
        if (tid < 64) {
          const unsigned* f = flags + tid * 4;
          for (;;) {
            unsigned mn = umin2(umin2(ld_rlx(f), ld_rlx(f + 1)),
                                umin2(ld_rlx(f + 2), ld_rlx(f + 3)));
            if (__all((int)(mn >= ep))) break;
            __builtin_amdgcn_s_sleep(1);
          }
        }
        if (tid == 0) (void)__hip_atomic_load(flags, __ATOMIC_ACQUIRE, __HIP_MEMORY_SCOPE_AGENT);
        __syncthreads();
        // column sums over 256 blocks (coalesced: tid spans one 2KB block chunk)
        float val = 0.f;
        const float* pp = part + tid;
#pragma unroll 8
        for (int bc = 0; bc < NBLK; ++bc) val += pp[(size_t)bc * 512];
        red[tid] = val;
        __syncthreads();
        float prod = 0.f;
        if (tid < 384) {
          int s = tid >> 7, row = tid & 127;
          prod = (red[row] + bs) * red[128 + (s << 7) + row];
        }
#pragma unroll
        for (int off = 1; off < 64; off <<= 1) prod += __shfl_xor(prod, off);
        if ((tid & 63) == 0) r2[tid >> 6] = prod;
        __syncthreads();
        if (tid == 0) {
          float l0 = r2[0] + r2[1] + xc[t * 4 + 0];
          float l1 = r2[2] + r2[3] + xc[t * 4 + 1];
          float l2 = r2[4] + r2[5] + xc[t * 4 + 2];
          float m = fmaxf(l0, fmaxf(l1, l2));
          float e0 = expf(l0 - m), e1 = expf(l1 - m), e2 = expf(l2 - m);
          float Z = e0 + e1 + e2;
          float w0 = e0 / Z * p0, w1 = e1 / Z * p1, w2 = e2 / Z * p2;
          int c = 0; float bestv = w0;
          if (w1 > bestv) { bestv = w1; c = 1; }
          if (w2 > bestv) { bestv = w2; c = 2; }
          p0 *= (c == 0) ? PEN : 1.f;
          p1 *= (c == 1) ? PEN : 1.f;
          p2 *= (c == 2) ? PEN : 1.f;
          float mx = fmaxf(p0, fmaxf(p1, p2));
          p0 /= mx; p1 /= mx; p2 /= mx;
          __hip_atomic_store(curk, ((unsigned)t << 2) | (unsigned)c,
                             __ATOMIC_RELEASE, __HIP_MEMORY_SCOPE_AGENT);
          curs = c;
        }
        __syncthreads();
        cur = curs;
      } else {
        if (tid == 0) {
          unsigned v;
          while (((v = ld_rlx(curk)) >> 2) != (unsigned)t) __builtin_amdgcn_s_sleep(1);
          (void)__hip_atomic_load(curk, __ATOMIC_ACQUIRE, __HIP_MEMORY_SCOPE_AGENT);
          curs = (int)(v & 3u);
        }
        __syncthreads();
        cur = curs;
      }
    }

    // ---- transpose x[:, t+1, :] one step ahead ----
    if (t + 1 < TT && tid < 128) {
      int idx = bid * 128 + tid;
      int b2 = idx >> 9, k = idx & 511;
      xTn[(k >> 2) * 256 + b2 * 4 + (k & 3)] =
          x[(size_t)b2 * TT * KK + (size_t)(t + 1) * KK + k];
    }

    // ---- layer 0 ----
    do_layer(tid, b, k0, j0, 0, bid, xTc, h0Tp,
             Wih_first + (size_t)cur * WSTRIDE,
             Whh + (size_t)(cur * 2 + 0) * WSTRIDE,
             bih + (size_t)(cur * 2 + 0) * G3, bhh + (size_t)(cur * 2 + 0) * G3,
             wsum, Wsel, h0Tn, nullptr, nullptr, part, red, r2);

    // ---- full barrier (flag-array, store-based; epoch 2t+1) ----
    {
      unsigned ep = 2u * (unsigned)t + 1u;
      __syncthreads();
      if (tid == 0)
        __hip_atomic_store(&flags[bid], ep, __ATOMIC_RELEASE, __HIP_MEMORY_SCOPE_AGENT);
      if (bid == 0 && tid < 64) {
        const unsigned* f = flags + tid * 4;
        for (;;) {
          unsigned mn = umin2(umin2(ld_rlx(f), ld_rlx(f + 1)),
                              umin2(ld_rlx(f + 2), ld_rlx(f + 3)));
          if (__all((int)(mn >= ep))) break;
          __builtin_amdgcn_s_sleep(1);
        }
        if (tid == 0)
          __hip_atomic_store(relw, ep, __ATOMIC_RELEASE, __HIP_MEMORY_SCOPE_AGENT);
      }
      if (tid == 0) {
        while (ld_rlx(relw) < ep) __builtin_amdgcn_s_sleep(1);
        (void)__hip_atomic_load(relw, __ATOMIC_ACQUIRE, __HIP_MEMORY_SCOPE_AGENT);
      }
      __syncthreads();
    }

    // ---- layer 1 ----
    float* o2 = (t == TT - 1) ? (out + (size_t)TT * BB * HH) : nullptr;
    do_layer(tid, b, k0, j0, 1, bid, h0Tn, h1Tp,
             Wih_rest + (size_t)cur * WSTRIDE,
             Whh + (size_t)(cur * 2 + 1) * WSTRIDE,
             bih + (size_t)(cur * 2 + 1) * G3, bhh + (size_t)(cur * 2 + 1) * G3,
             wsum, Wsel, h1Tn, out + (size_t)t * BB * HH, o2, part, red, r2);

    // ---- layer-1 done: publish flags (epoch 2t+2); block 0 fans in next step ----
    __syncthreads();
    if (tid == 0)
      __hip_atomic_store(&flags[bid], 2u * (unsigned)t + 2u,
                         __ATOMIC_RELEASE, __HIP_MEMORY_SCOPE_AGENT);
  }
}

// ---------------------------------------------------------------------------
extern "C" void kernel_launch(void* const* d_in, const int* in_sizes, int n_in,
                              void* d_out, int out_size, void* d_ws, size_t ws_size,
                              hipStream_t stream) {
  const float* x         = (const float*)d_in[0];
  const float* Wih_first = (const float*)d_in[1];
  const float* Wih_rest  = (const float*)d_in[2];
  const float* Whh       = (const float*)d_in[3];
  const float* bih       = (const float*)d_in[4];
  const float* bhh       = (const float*)d_in[5];
  const float* Wlw       = (const float*)d_in[6];
  const float* blw       = (const float*)d_in[7];
  const float* Wsel      = (const float*)d_in[8];
  const float* bsel      = (const float*)d_in[9];
  float* out = (float*)d_out;
  float* ws  = (float*)d_ws;

  float* xT    = ws;                       // 2 * 32768
  float* h0T   = xT + 2 * SLAB;            // 2 * 32768
  float* h1T   = h0T + 2 * SLAB;           // 2 * 32768
  float* part  = h1T + 2 * SLAB;           // 256 * 512
  float* xc    = part + NBLK * 512;        // 512 * 4
  float* wsum  = xc + TT * 4;              // 512
  float* bsumb = wsum + HH;                // 1
  unsigned* flags = (unsigned*)(bsumb + 1);  // 256
  unsigned* relw  = flags + 256;
  unsigned* curk  = relw + 1;

  k_pre_xc<<<dim3(TT), 256, 0, stream>>>(x, Wsel, bsel, xc);
  k_pre_misc<<<dim3(64), 256, 0, stream>>>(Wlw, blw, x, wsum, bsumb,
                                           xT, h0T, h1T, flags, relw, curk);
  k_persist<<<dim3(NBLK), NTHR, 0, stream>>>(x, Wih_first, Wih_rest, Whh, bih, bhh,
                                             Wsel, wsum, bsumb, xc,
                                             xT, h0T, h1T, part, out,
                                             flags, relw, curk);
}

// Round 6
// 15875.668 us; speedup vs baseline: 5.0378x; 2.0542x over previous
//
#include <hip/hip_runtime.h>
#include <math.h>

#define BB 64
#define TT 512
#define HH 512
#define KK 512
#define G3 1536
#define PEN 0.7f
#define NBLK 256
#define NTHR 512
#define SLAB 32768               // 64*512 floats (one transposed activation slab)
#define WSTRIDE ((size_t)(G3 * KK))

// ---------------------------------------------------------------------------
// L2-bypass (coherent-point) access helpers. sc0 sc1 = bypass L1 and L2, so
// reads always see MALL-fresh data and writes are immediately agent-visible.
// NO acquire/release atomics anywhere in the hot loop -> no buffer_inv/wbl2
// -> weights and x stay L2-resident across all 512 steps.
__device__ __forceinline__ float4 ldcv4(const float* p) {
  float4 r;
  asm volatile("global_load_dwordx4 %0, %1, off sc0 sc1" : "=v"(r) : "v"(p));
  return r;
}
__device__ __forceinline__ void ld1_issue(float* dst, const float* p) {
  asm volatile("global_load_dword %0, %1, off sc0 sc1" : "=v"(*dst) : "v"(p));
}
__device__ __forceinline__ void stwt1(float* p, float v) {
  asm volatile("global_store_dword %0, %1, off sc0 sc1" :: "v"(p), "v"(v) : "memory");
}
__device__ __forceinline__ void vwait() {
  asm volatile("s_waitcnt vmcnt(0)" ::: "memory");
  __builtin_amdgcn_sched_barrier(0);
}
__device__ __forceinline__ unsigned umin2(unsigned a, unsigned b) { return a < b ? a : b; }
__device__ __forceinline__ void st_flag(unsigned* p, unsigned v) {
  __hip_atomic_store(p, v, __ATOMIC_RELAXED, __HIP_MEMORY_SCOPE_AGENT);
}
// wave0 polls all 256 block flags (monotonic epochs; stale read -> re-poll)
__device__ __forceinline__ void poll_all(const unsigned* flags, unsigned ep) {
  const unsigned* p = flags + (threadIdx.x & 63) * 4;
  for (;;) {
    uint4 v;
    asm volatile("global_load_dwordx4 %0, %1, off sc0 sc1" : "=v"(v) : "v"(p));
    vwait();
    unsigned mn = umin2(umin2(v.x, v.y), umin2(v.z, v.w));
    if (__all((int)(mn >= ep))) break;
    __builtin_amdgcn_s_sleep(2);
  }
}
__device__ __forceinline__ void poll8(const unsigned* flag8, unsigned ep) {
  const unsigned* p = flag8 + (threadIdx.x & 7);
  for (;;) {
    unsigned v;
    asm volatile("global_load_dword %0, %1, off sc0 sc1" : "=v"(v) : "v"(p));
    vwait();
    if (__all((int)(v >= ep))) break;
    __builtin_amdgcn_s_sleep(2);
  }
}

// ---------------------------------------------------------------------------
// pre 1: xc[t][s] = sum_b x[b,t,:] . Wsel[s,512:] + B*bsel[s]
__global__ void k_pre_xc(const float* __restrict__ x, const float* __restrict__ Wsel,
                         const float* __restrict__ bsel, float* __restrict__ xc) {
  int t = blockIdx.x, tid = threadIdx.x;
  __shared__ float xs[512];
  __shared__ float a0[256], a1[256], a2[256];
  for (int i = tid; i < 512; i += 256) {
    float s = 0.f;
    const float* px = x + (size_t)t * KK + i;
    for (int b = 0; b < BB; ++b) s += px[(size_t)b * TT * KK];
    xs[i] = s;
  }
  __syncthreads();
  float c0 = 0.f, c1 = 0.f, c2 = 0.f;
  for (int i = tid; i < 512; i += 256) {
    float v = xs[i];
    c0 += v * Wsel[512 + i];
    c1 += v * Wsel[1024 + 512 + i];
    c2 += v * Wsel[2048 + 512 + i];
  }
  a0[tid] = c0; a1[tid] = c1; a2[tid] = c2;
  __syncthreads();
  for (int off = 128; off; off >>= 1) {
    if (tid < off) { a0[tid] += a0[tid + off]; a1[tid] += a1[tid + off]; a2[tid] += a2[tid + off]; }
    __syncthreads();
  }
  if (tid == 0) {
    xc[t * 4 + 0] = a0[0] + 64.f * bsel[0];
    xc[t * 4 + 1] = a1[0] + 64.f * bsel[1];
    xc[t * 4 + 2] = a2[0] + 64.f * bsel[2];
  }
}

// pre 2: wsum/bsum, zero t=0 hidden slabs, transpose x[:,0,:] into xT2 slab0,
// zero all sync words
__global__ void k_pre_misc(const float* __restrict__ Wlw, const float* __restrict__ blw,
                           const float* __restrict__ x,
                           float* __restrict__ wsum, float* __restrict__ bsumb,
                           float* __restrict__ xT0,
                           float* __restrict__ h0T0, float* __restrict__ h1T0,
                           unsigned* __restrict__ flags, unsigned* __restrict__ flag8) {
  int gtid = blockIdx.x * 256 + threadIdx.x;        // 64 blocks * 256
  for (int i = gtid; i < SLAB; i += 64 * 256) { h0T0[i] = 0.f; h1T0[i] = 0.f; }
  for (int i = gtid; i < SLAB; i += 64 * 256) {
    int b = i >> 9, k = i & 511;
    xT0[(k >> 2) * 256 + b * 4 + (k & 3)] = x[(size_t)b * TT * KK + k];
  }
  if (blockIdx.x == 0) {
    int tid = threadIdx.x;
    if (tid < 256) flags[tid] = 0u;
    if (tid < 8) flag8[tid] = 0u;
    for (int h = tid; h < 512; h += 256) {
      float s = 0.f;
      for (int g = 0; g < 512; ++g) s += Wlw[(size_t)g * 512 + h];
      wsum[h] = s;
    }
    __shared__ float red[256];
    float s = 0.f;
    for (int i = tid; i < 512; i += 256) s += blw[i];
    red[tid] = s;
    __syncthreads();
    for (int off = 128; off; off >>= 1) {
      if (tid < off) red[tid] += red[tid + off];
      __syncthreads();
    }
    if (tid == 0) *bsumb = red[0];
  }
}

// pre 3 (big-ws mode): transpose ALL x into xTall[t][k/4][b*4+(k&3)] (read-only
// -> cached reads forever in the persistent kernel)
__global__ void k_pre_xt(const float* __restrict__ x, float* __restrict__ xTall) {
  int t = blockIdx.x, tid = threadIdx.x;
  float* dst = xTall + (size_t)t * SLAB;
  const float* src = x + (size_t)t * KK;
  for (int i = tid; i < SLAB; i += 256) {
    int b = i >> 9, k = i & 511;
    dst[(k >> 2) * 256 + b * 4 + (k & 3)] = src[(size_t)b * TT * KK + k];
  }
}

// ---------------------------------------------------------------------------
// One GRU layer. wave = K/8 slice x both j; lane = b. Act/h operands are
// register-prefetched bypass bursts (8 x float4 issue -> one vmcnt(0)), then
// a pure FMA block with L2-cached wave-uniform weight loads.
template<int ACT_CACHED>
__device__ __forceinline__ void do_layer(
    int tid, int b, int k0, int j0, int lidx, int bid,
    const float* __restrict__ act, const float* __restrict__ hT,
    const float* __restrict__ Wih, const float* __restrict__ Whh,
    const float* __restrict__ bihL, const float* __restrict__ bhhL,
    const float* __restrict__ wsum, const float* __restrict__ Wsel,
    float* __restrict__ houtT, float* __restrict__ houtN, float* __restrict__ houtN2,
    float* __restrict__ part, float* red, float* r2) {
  int w = tid >> 6;
  const float* a4p = act + (k0 >> 2) * 256 + b * 4;
  const float* h4p = hT + (k0 >> 2) * 256 + b * 4;
  const float* wi0r = Wih + (size_t)(j0 + 0) * KK + k0;
  const float* wi1r = Wih + (size_t)(j0 + 1) * KK + k0;
  const float* wi0z = Wih + (size_t)(512 + j0 + 0) * KK + k0;
  const float* wi1z = Wih + (size_t)(512 + j0 + 1) * KK + k0;
  const float* wi0n = Wih + (size_t)(1024 + j0 + 0) * KK + k0;
  const float* wi1n = Wih + (size_t)(1024 + j0 + 1) * KK + k0;
  const float* wh0r = Whh + (size_t)(j0 + 0) * KK + k0;
  const float* wh1r = Whh + (size_t)(j0 + 1) * KK + k0;
  const float* wh0z = Whh + (size_t)(512 + j0 + 0) * KK + k0;
  const float* wh1z = Whh + (size_t)(512 + j0 + 1) * KK + k0;
  const float* wh0n = Whh + (size_t)(1024 + j0 + 0) * KK + k0;
  const float* wh1n = Whh + (size_t)(1024 + j0 + 1) * KK + k0;
  float ai0r = 0.f, ai1r = 0.f, ai0z = 0.f, ai1z = 0.f, ai0n = 0.f, ai1n = 0.f;
  float ah0r = 0.f, ah1r = 0.f, ah0z = 0.f, ah1z = 0.f, ah0n = 0.f, ah1n = 0.f;
  float4 A[8], Hv[8];
  for (int half = 0; half < 2; ++half) {
    const float* ab = a4p + half * 2048;
    const float* hb = h4p + half * 2048;
#pragma unroll
    for (int i = 0; i < 8; ++i) {
      if (ACT_CACHED) A[i] = *(const float4*)(ab + i * 256);
      else            A[i] = ldcv4(ab + i * 256);
      Hv[i] = ldcv4(hb + i * 256);
    }
    vwait();
#pragma unroll
    for (int c = 0; c < 8; ++c) {
      const int kc = half * 8 + c;
      const float4 a4 = A[c];
      const float4 h4 = Hv[c];
      float4 q;
#define DOTW(acc, ptr, vv) q = *(const float4*)((ptr) + kc * 4); \
      acc += vv.x * q.x + vv.y * q.y + vv.z * q.z + vv.w * q.w;
      DOTW(ai0r, wi0r, a4) DOTW(ai1r, wi1r, a4)
      DOTW(ai0z, wi0z, a4) DOTW(ai1z, wi1z, a4)
      DOTW(ai0n, wi0n, a4) DOTW(ai1n, wi1n, a4)
      DOTW(ah0r, wh0r, h4) DOTW(ah1r, wh1r, h4)
      DOTW(ah0z, wh0z, h4) DOTW(ah1z, wh1z, h4)
      DOTW(ah0n, wh0n, h4) DOTW(ah1n, wh1n, h4)
#undef DOTW
    }
  }
  int base = (w * 12) * 64 + b;
  red[base + 0 * 64] = ai0r; red[base + 1 * 64] = ai0z; red[base + 2 * 64] = ai0n;
  red[base + 3 * 64] = ah0r; red[base + 4 * 64] = ah0z; red[base + 5 * 64] = ah0n;
  red[base + 6 * 64] = ai1r; red[base + 7 * 64] = ai1z; red[base + 8 * 64] = ai1n;
  red[base + 9 * 64] = ah1r; red[base + 10 * 64] = ah1z; red[base + 11 * 64] = ah1n;
  __syncthreads();
  if (tid < 128) {
    int bb = tid & 63, jl = tid >> 6;
    int j = j0 + jl;
    float hpv;
    ld1_issue(&hpv, hT + (j >> 2) * 256 + bb * 4 + (j & 3));  // overlap with reduce
    float sir = 0.f, siz = 0.f, sinn = 0.f, shr = 0.f, shz = 0.f, shn = 0.f;
#pragma unroll
    for (int ww = 0; ww < 8; ++ww) {
      int o = (ww * 12 + jl * 6) * 64 + bb;
      sir += red[o]; siz += red[o + 64]; sinn += red[o + 128];
      shr += red[o + 192]; shz += red[o + 256]; shn += red[o + 320];
    }
    vwait();
    float air = sir + bihL[j],         ahr = shr + bhhL[j];
    float aiz = siz + bihL[j + 512],   ahz = shz + bhhL[j + 512];
    float ain = sinn + bihL[j + 1024], ahn = shn + bhhL[j + 1024];
    float rg = 1.f / (1.f + expf(-(air + ahr)));
    float zg = 1.f / (1.f + expf(-(aiz + ahz)));
    float ng = tanhf(ain + rg * ahn);
    float hv = (1.f - zg) * ng + zg * hpv;
    stwt1(houtT + (j >> 2) * 256 + bb * 4 + (j & 3), hv);
    if (houtN) houtN[(size_t)bb * HH + j] = hv;
    if (houtN2) houtN2[(size_t)bb * HH + j] = hv;
    r2[jl * 256 + 0 * 64 + bb] = hv * wsum[j];
    r2[jl * 256 + 1 * 64 + bb] = hv * Wsel[j];
    r2[jl * 256 + 2 * 64 + bb] = hv * Wsel[1024 + j];
    r2[jl * 256 + 3 * 64 + bb] = hv * Wsel[2048 + j];
  }
  __syncthreads();
  if (tid < 64) {
    float* pb = part + (size_t)bid * 512;
    stwt1(pb + lidx * 64 + tid,       r2[tid]       + r2[256 + tid]);
    stwt1(pb + 128 + lidx * 64 + tid, r2[64 + tid]  + r2[256 + 64 + tid]);
    stwt1(pb + 256 + lidx * 64 + tid, r2[128 + tid] + r2[256 + 128 + tid]);
    stwt1(pb + 384 + lidx * 64 + tid, r2[192 + tid] + r2[256 + 192 + tid]);
  }
}

// ---------------------------------------------------------------------------
template<int XM>
__global__ __launch_bounds__(NTHR, 2) void k_persist(
    const float* __restrict__ x,
    const float* __restrict__ Wih_first, const float* __restrict__ Wih_rest,
    const float* __restrict__ Whh,
    const float* __restrict__ bih, const float* __restrict__ bhh,
    const float* __restrict__ Wsel,
    const float* __restrict__ wsum, const float* __restrict__ bsumb,
    const float* __restrict__ xc,
    float* __restrict__ xzone, float* __restrict__ h0T, float* __restrict__ h1T,
    float* __restrict__ part, float* __restrict__ partial2,
    float* __restrict__ out,
    unsigned* __restrict__ flags, unsigned* __restrict__ flag8) {
  __shared__ float red[8 * 12 * 64];   // 24 KB wave partials / router scratch
  __shared__ float r2[2 * 4 * 64];     // j-pair reduce / router wave sums
  int tid = threadIdx.x, bid = blockIdx.x;
  int b = tid & 63;
  int k0 = __builtin_amdgcn_readfirstlane(((int)threadIdx.x >> 6) << 6);
  int j0 = bid * 2;
  float p0 = PEN, p1 = 1.f, p2 = 1.f;   // penalty state, replicated (deterministic)
  int cur = 0;
  float bs = *bsumb;

  for (int t = 0; t < TT; ++t) {
    int par = t & 1;
    const float* h0Tp = h0T + par * SLAB;
    float* h0Tn = h0T + (par ^ 1) * SLAB;
    const float* h1Tp = h1T + par * SLAB;
    float* h1Tn = h1T + (par ^ 1) * SLAB;
    const float* act0;
    float* xTn = nullptr;
    if (XM) act0 = xzone + (size_t)t * SLAB;
    else { act0 = xzone + par * SLAB; xTn = xzone + (par ^ 1) * SLAB; }

    if (t > 0) {
      // ---- leaderless router: wait for the 8 reducers' partial2 of this step,
      // then EVERY block computes logits/cur/p redundantly (identical order) ----
      if (tid < 64) poll8(flag8, (unsigned)t);
      __syncthreads();
      float g0, g1, g2, g3, g4, g5, g6, g7;
      ld1_issue(&g0, partial2 + 0 * 512 + tid);
      ld1_issue(&g1, partial2 + 1 * 512 + tid);
      ld1_issue(&g2, partial2 + 2 * 512 + tid);
      ld1_issue(&g3, partial2 + 3 * 512 + tid);
      ld1_issue(&g4, partial2 + 4 * 512 + tid);
      ld1_issue(&g5, partial2 + 5 * 512 + tid);
      ld1_issue(&g6, partial2 + 6 * 512 + tid);
      ld1_issue(&g7, partial2 + 7 * 512 + tid);
      vwait();
      red[tid] = ((g0 + g1) + (g2 + g3)) + ((g4 + g5) + (g6 + g7));
      __syncthreads();
      float prod = 0.f;
      if (tid < 384) {
        int s = tid >> 7, row = tid & 127;
        prod = (red[row] + bs) * red[128 + (s << 7) + row];
      }
#pragma unroll
      for (int off = 1; off < 64; off <<= 1) prod += __shfl_xor(prod, off);
      if ((tid & 63) == 0) r2[tid >> 6] = prod;
      __syncthreads();
      float l0 = r2[0] + r2[1] + xc[t * 4 + 0];
      float l1 = r2[2] + r2[3] + xc[t * 4 + 1];
      float l2 = r2[4] + r2[5] + xc[t * 4 + 2];
      float m = fmaxf(l0, fmaxf(l1, l2));
      float e0 = expf(l0 - m), e1 = expf(l1 - m), e2 = expf(l2 - m);
      float Z = e0 + e1 + e2;
      float w0 = e0 / Z * p0, w1 = e1 / Z * p1, w2 = e2 / Z * p2;
      cur = 0;
      float bestv = w0;
      if (w1 > bestv) { bestv = w1; cur = 1; }
      if (w2 > bestv) { bestv = w2; cur = 2; }
      p0 *= (cur == 0) ? PEN : 1.f;
      p1 *= (cur == 1) ? PEN : 1.f;
      p2 *= (cur == 2) ? PEN : 1.f;
      float mx = fmaxf(p0, fmaxf(p1, p2));
      p0 /= mx; p1 /= mx; p2 /= mx;
      __syncthreads();   // protect red/r2 reuse by the layer below
    }

    // ---- small-ws mode: stage x[:, t+1, :] transpose (write-through) ----
    if (!XM && t + 1 < TT && tid < 128) {
      int idx = bid * 128 + tid;
      int b2 = idx >> 9, k = idx & 511;
      stwt1(xTn + (k >> 2) * 256 + b2 * 4 + (k & 3),
            x[(size_t)b2 * TT * KK + (size_t)(t + 1) * KK + k]);
    }

    // ---- layer 0 ----
    do_layer<XM>(tid, b, k0, j0, 0, bid, act0, h0Tp,
                 Wih_first + (size_t)cur * WSTRIDE,
                 Whh + (size_t)(cur * 2 + 0) * WSTRIDE,
                 bih + (size_t)(cur * 2 + 0) * G3, bhh + (size_t)(cur * 2 + 0) * G3,
                 wsum, Wsel, h0Tn, nullptr, nullptr, part, red, r2);
    __syncthreads();                    // drains each wave's write-through stores
    if (tid == 0) st_flag(&flags[bid], 2u * (unsigned)t + 1u);

    // ---- leaderless full barrier: all blocks poll all 256 flags ----
    if (tid < 64) poll_all(flags, 2u * (unsigned)t + 1u);
    __syncthreads();

    // ---- layer 1 ----
    float* o2 = (t == TT - 1) ? (out + (size_t)TT * BB * HH) : nullptr;
    do_layer<0>(tid, b, k0, j0, 1, bid, h0Tn, h1Tp,
                Wih_rest + (size_t)cur * WSTRIDE,
                Whh + (size_t)(cur * 2 + 1) * WSTRIDE,
                bih + (size_t)(cur * 2 + 1) * G3, bhh + (size_t)(cur * 2 + 1) * G3,
                wsum, Wsel, h1Tn, out + (size_t)t * BB * HH, o2, part, red, r2);
    __syncthreads();
    if (tid == 0) st_flag(&flags[bid], 2u * (unsigned)t + 2u);

    // ---- 8 spread reducer blocks: part -> partial2 for next step's router ----
    if (bid < 8 && t + 1 < TT) {
      if (tid < 64) poll_all(flags, 2u * (unsigned)t + 2u);
      __syncthreads();
      float a[32];
#pragma unroll
      for (int r = 0; r < 32; ++r)
        ld1_issue(&a[r], part + (size_t)(32 * bid + r) * 512 + tid);
      vwait();
      float s = 0.f;
#pragma unroll
      for (int r = 0; r < 32; ++r) s += a[r];
      stwt1(partial2 + bid * 512 + tid, s);
      __syncthreads();                  // drain write-through stores
      if (tid == 0) st_flag(&flag8[bid], (unsigned)t + 1u);
    }
  }
}

// ---------------------------------------------------------------------------
extern "C" void kernel_launch(void* const* d_in, const int* in_sizes, int n_in,
                              void* d_out, int out_size, void* d_ws, size_t ws_size,
                              hipStream_t stream) {
  const float* x         = (const float*)d_in[0];
  const float* Wih_first = (const float*)d_in[1];
  const float* Wih_rest  = (const float*)d_in[2];
  const float* Whh       = (const float*)d_in[3];
  const float* bih       = (const float*)d_in[4];
  const float* bhh       = (const float*)d_in[5];
  const float* Wlw       = (const float*)d_in[6];
  const float* blw       = (const float*)d_in[7];
  const float* Wsel      = (const float*)d_in[8];
  const float* bsel      = (const float*)d_in[9];
  float* out = (float*)d_out;
  float* ws  = (float*)d_ws;

  float* h0T      = ws;                         // 2*SLAB
  float* h1T      = h0T + 2 * SLAB;             // 2*SLAB
  float* xT2      = h1T + 2 * SLAB;             // 2*SLAB (small-ws act staging)
  float* part     = xT2 + 2 * SLAB;             // 256*512
  float* partial2 = part + NBLK * 512;          // 8*512
  float* xc       = partial2 + 8 * 512;         // 512*4
  float* wsum     = xc + TT * 4;                // 512
  float* bsumb    = wsum + HH;                  // 1 (+3 pad)
  unsigned* flags = (unsigned*)(bsumb + 4);     // 256 (16B aligned)
  unsigned* flag8 = flags + 256;                // 8
  size_t hdr_floats = (size_t)((float*)(flag8 + 8) - ws);
  hdr_floats = (hdr_floats + 3) & ~(size_t)3;
  float* xTall = ws + hdr_floats;               // 512*SLAB (big-ws mode)
  size_t need_big = (hdr_floats + (size_t)TT * SLAB) * sizeof(float);

  k_pre_xc<<<dim3(TT), 256, 0, stream>>>(x, Wsel, bsel, xc);
  k_pre_misc<<<dim3(64), 256, 0, stream>>>(Wlw, blw, x, wsum, bsumb,
                                           xT2, h0T, h1T, flags, flag8);
  if (ws_size >= need_big) {
    k_pre_xt<<<dim3(TT), 256, 0, stream>>>(x, xTall);
    k_persist<1><<<dim3(NBLK), NTHR, 0, stream>>>(x, Wih_first, Wih_rest, Whh, bih, bhh,
                                                  Wsel, wsum, bsumb, xc,
                                                  xTall, h0T, h1T, part, partial2,
                                                  out, flags, flag8);
  } else {
    k_persist<0><<<dim3(NBLK), NTHR, 0, stream>>>(x, Wih_first, Wih_rest, Whh, bih, bhh,
                                                  Wsel, wsum, bsumb, xc,
                                                  xT2, h0T, h1T, part, partial2,
                                                  out, flags, flag8);
  }
}